// Round 8
// baseline (1209.538 us; speedup 1.0000x reference)
//
#include <hip/hip_runtime.h>

// FiLM forward == fixed linear map K (192x768) applied to inputs (8,768,64), K rebuilt
// on-device each call from spec weights + HiPPO-LegT constants.
// Inversion: pivoted Gauss-Jordan with VIRTUAL pivoting (no row swaps; per-row used
// flags + recorded pivot sequence; right half ends as P*Minv, un-permuted in k_y0).
// Same arithmetic as classic partial pivoting -- LegT A is severely non-normal, so
// from-scratch Neumann/NS overflows f32 (round-3 lesson); GJ+f64 Newton is required.
// U-GEMM: fp16 2-way-split MFMA (16x16x32_f16, hh/hl/lh; exact 2^k scaling).
// K-GEMM: 64x64-tile LDS f32 GEMM (round-8: was uncoalesced per-thread dot, 51us).
// Krylov: doubling all the way to L=512 (round-8: replaces 5 serial k_chunk launches).
// Chunk-phase scratch C8/Seg alias the (dead by then) inversion/AP regions.

#define OFF_MF64  0
#define OFF_YA    1572864
#define OFF_YB    3145728
#define OFF_Z     4718592
#define OFF_W0    6291456     // [3][256][512] f32 augmented [M | I], in-place GJ
#define OFF_F     7864320     // [3][32][256] f32 per-panel elementary factors
#define OFF_PIV   7962624     // [3][256] int pivot sequence
#define OFF_USED  7966720     // [3][256] int used flags
#define OFF_AP0   10223616
#define OFF_AP1   11010048
#define OFF_BD    11796480
#define OFF_V     11800576
#define OFF_EM    14159872
#define OFF_P     14749696
#define OFF_K     16125952
#define OFF_WT    16715776
#define OFF_U     29298688
// aliases (live only during chunk phase; inversion/AP regions dead by then)
#define OFF_C8    0
#define OFF_SEG   11010048

typedef _Float16 half8 __attribute__((ext_vector_type(8)));
typedef float f32x4 __attribute__((ext_vector_type(4)));

__device__ __forceinline__ double a_entry(int i, int j){
  double base = (i < j) ? -1.0 : (((i - j) & 1) ? 1.0 : -1.0);  // (-1)^(i-j+1) for i>=j
  return base * (double)(2*i + 1);
}

// Build Mf64 = I - dt/2*A, GJ working buffer W0 = [M_f32 | I], zero used flags
__global__ void k_init(double* __restrict__ Mf64, float* __restrict__ W0,
                       int* __restrict__ usedg){
  int s = blockIdx.y, i = blockIdx.x, j = threadIdx.x;
  double dt = (1.0 / 192.0) / (double)(1 << s);
  double m = ((i == j) ? 1.0 : 0.0) - 0.5 * dt * a_entry(i, j);
  Mf64[((size_t)s*256 + i)*256 + j] = m;
  float* w = W0 + ((size_t)s*256 + i)*512;
  w[j] = (float)m;
  w[256 + j] = (i == j) ? 1.0f : 0.0f;
  if (j == 0) usedg[s*256 + i] = 0;
}

// Panel factorization, virtual pivoting: one row per thread in registers; argmax over
// unused rows; winner scales in place and publishes; F/pivots accumulate in registers.
__global__ __launch_bounds__(256) void k_panelF(const float* __restrict__ W0in,
                                                float* __restrict__ Fg,
                                                int* __restrict__ pivg,
                                                int* __restrict__ usedg, int kpanel){
  int s = blockIdx.x;
  const float* buf = W0in + (size_t)s*131072;
  float* Fb = Fg + (size_t)s*8192;
  int r = threadIdx.x;
  int c0 = kpanel*32;
  float row[32], freg[32];
  int pv[32];
  #pragma unroll
  for (int j = 0; j < 32; j += 4){
    float4 v = *(const float4*)&buf[(size_t)r*512 + c0 + j];
    row[j] = v.x; row[j+1] = v.y; row[j+2] = v.z; row[j+3] = v.w;
  }
  int used = usedg[s*256 + r];
  __shared__ float prow[2][32];
  __shared__ float wv[4];
  __shared__ int wi[4];
  #pragma unroll
  for (int l = 0; l < 32; ++l){
    float a = used ? -1.0f : fabsf(row[l]);
    int bi = r;
    #pragma unroll
    for (int off = 32; off > 0; off >>= 1){
      float oa = __shfl_xor(a, off);
      int ob = __shfl_xor(bi, off);
      if (oa > a || (oa == a && ob < bi)){ a = oa; bi = ob; }
    }
    if ((r & 63) == 0){ wv[r >> 6] = a; wi[r >> 6] = bi; }
    __syncthreads();
    float best = wv[0]; int piv = wi[0];
    #pragma unroll
    for (int w = 1; w < 4; ++w){
      if (wv[w] > best || (wv[w] == best && wi[w] < piv)){ best = wv[w]; piv = wi[w]; }
    }
    pv[l] = piv;
    if (r == piv){
      float inv = 1.0f / row[l];
      freg[l] = inv;
      used = 1;
      #pragma unroll
      for (int j = 0; j < 32; ++j){ row[j] *= inv; prow[l & 1][j] = row[j]; }
    }
    __syncthreads();
    float f = row[l];
    if (r != piv){
      freg[l] = f;
      #pragma unroll
      for (int j = 0; j < 32; ++j) row[j] -= f * prow[l & 1][j];
    }
  }
  #pragma unroll
  for (int l = 0; l < 32; ++l) Fb[l*256 + r] = freg[l];
  usedg[s*256 + r] = used;
  if (r == 0){
    #pragma unroll
    for (int l = 0; l < 32; ++l) pivg[s*256 + kpanel*32 + l] = pv[l];
  }
}

// Trailing update: replay the 32 elementary ops (virtual pivots) on a 32-col tile.
__global__ __launch_bounds__(256) void k_trailF(float* __restrict__ W0,
                                                const float* __restrict__ Fg,
                                                const int* __restrict__ pivg, int kpanel){
  int s = blockIdx.y;
  float* buf = W0 + (size_t)s*131072;
  const float* Fb = Fg + (size_t)s*8192;
  const int* pivb = pivg + s*256 + kpanel*32;
  int r = threadIdx.x;
  int col0 = 32*(kpanel+1) + blockIdx.x*32;
  float row[32], f[32];
  #pragma unroll
  for (int j = 0; j < 32; j += 4){
    float4 v = *(const float4*)&buf[(size_t)r*512 + col0 + j];
    row[j] = v.x; row[j+1] = v.y; row[j+2] = v.z; row[j+3] = v.w;
  }
  #pragma unroll
  for (int l = 0; l < 32; ++l) f[l] = Fb[l*256 + r];
  __shared__ float prow[2][32];
  __shared__ int pvs[32];
  if (r < 32) pvs[r] = pivb[r];
  __syncthreads();
  #pragma unroll
  for (int l = 0; l < 32; ++l){
    int piv = pvs[l];
    if (r == piv){
      #pragma unroll
      for (int j = 0; j < 32; ++j){ row[j] *= f[l]; prow[l & 1][j] = row[j]; }
    }
    __syncthreads();
    if (r != piv){
      #pragma unroll
      for (int j = 0; j < 32; ++j) row[j] -= f[l] * prow[l & 1][j];
    }
  }
  #pragma unroll
  for (int j = 0; j < 32; j += 4){
    float4 v = make_float4(row[j], row[j+1], row[j+2], row[j+3]);
    *(float4*)&buf[(size_t)r*512 + col0 + j] = v;
  }
}

// Y[l] = W0right[piv_l]  (un-permute: right half holds P*Minv)
__global__ void k_y0(const float* __restrict__ W, const int* __restrict__ pivg,
                     double* __restrict__ Y){
  int s = blockIdx.y, i = blockIdx.x, j = threadIdx.x;
  int p = pivg[s*256 + i];
  Y[((size_t)s*256 + i)*256 + j] = (double)W[((size_t)s*256 + p)*512 + 256 + j];
}

// Z = M @ Y  (f64)
__global__ void k_mmZ(const double* __restrict__ M, const double* __restrict__ Y,
                      double* __restrict__ Z){
  int s = blockIdx.y;
  const double* A = M + (size_t)s*65536;
  const double* B = Y + (size_t)s*65536;
  int c = threadIdx.x, r0 = blockIdx.x * 8;
  double acc[8] = {0,0,0,0,0,0,0,0};
  for (int j = 0; j < 256; ++j){
    double b = B[(size_t)j*256 + c];
    #pragma unroll
    for (int q = 0; q < 8; ++q) acc[q] += A[(size_t)(r0+q)*256 + j] * b;
  }
  #pragma unroll
  for (int q = 0; q < 8; ++q) Z[(size_t)s*65536 + (size_t)(r0+q)*256 + c] = acc[q];
}

// Yn = 2Y - Y @ Z  (Newton-Schulz step, f64)
__global__ void k_mmN(const double* __restrict__ Y, const double* __restrict__ Z,
                      double* __restrict__ Yn){
  int s = blockIdx.y;
  const double* A = Y + (size_t)s*65536;
  const double* B = Z + (size_t)s*65536;
  int c = threadIdx.x, r0 = blockIdx.x * 8;
  double acc[8] = {0,0,0,0,0,0,0,0};
  for (int j = 0; j < 256; ++j){
    double b = B[(size_t)j*256 + c];
    #pragma unroll
    for (int q = 0; q < 8; ++q) acc[q] += A[(size_t)(r0+q)*256 + j] * b;
  }
  #pragma unroll
  for (int q = 0; q < 8; ++q)
    Yn[(size_t)s*65536 + (size_t)(r0+q)*256 + c] =
      2.0 * A[(size_t)(r0+q)*256 + c] - acc[q];
}

// Ad = 2*Minv - I (f32, into AP0); Bd = Minv @ (dt*B); V row0 = Bd
__global__ void k_final(const double* __restrict__ Y, float* __restrict__ Ad,
                        float* __restrict__ Bd, float* __restrict__ V){
  int s = blockIdx.y;
  const double* Ys = Y + (size_t)s*65536;
  if (blockIdx.x < 64){
    int c = threadIdx.x, r0 = blockIdx.x * 4;
    #pragma unroll
    for (int q = 0; q < 4; ++q){
      double v = 2.0 * Ys[(size_t)(r0+q)*256 + c] - ((r0+q) == c ? 1.0 : 0.0);
      Ad[(size_t)s*65536 + (size_t)(r0+q)*256 + c] = (float)v;
    }
  } else {
    int i = threadIdx.x;
    double dt = (1.0 / 192.0) / (double)(1 << s);
    double acc = 0.0;
    for (int j = 0; j < 256; ++j){
      double bj = dt * ((j & 1) ? -1.0 : 1.0) * (double)(2*j + 1);
      acc += Ys[(size_t)i*256 + j] * bj;
    }
    float b = (float)acc;
    Bd[s*256 + i] = b;
    V[((size_t)s*768 + 0)*256 + i] = b;
  }
}

// Legendre eval matrix (last 192 rows), f64 recurrence
__global__ void k_em(float* __restrict__ em){
  int s = blockIdx.x, t = threadIdx.x;
  int T = 192 << s;
  double dt = (1.0 / 192.0) / (double)(1 << s);
  double x = 1.0 - 2.0 * ((double)(T - 192 + t) * dt);
  float* row = em + ((size_t)s*192 + t)*256;
  double p0 = 1.0, p1 = x;
  row[0] = 1.0f; row[1] = (float)x;
  for (int n = 1; n < 255; ++n){
    double p2 = ((double)(2*n+1) * x * p1 - (double)n * p0) / (double)(n+1);
    row[n+1] = (float)p2;
    p0 = p1; p1 = p2;
  }
}

// one doubling level: Pout = Pin@Pin (bx<64, skipped if noSquare);
// V[L..min(2L,768)) = Pin @ V[0..L) (bx>=64)
__global__ void k_level(const float* __restrict__ Pin, float* __restrict__ Pout,
                        float* __restrict__ V, int L, int noSquare){
  int s = blockIdx.y;
  const float* A = Pin + (size_t)s*65536;
  int bx = blockIdx.x;
  if (bx < 64){
    if (noSquare) return;
    int c = threadIdx.x, r0 = bx * 4;
    float acc[4] = {0,0,0,0};
    for (int k = 0; k < 256; ++k){
      float b = A[(size_t)k*256 + c];
      #pragma unroll
      for (int q = 0; q < 4; ++q) acc[q] += A[(size_t)(r0+q)*256 + k] * b;
    }
    #pragma unroll
    for (int q = 0; q < 4; ++q) Pout[(size_t)s*65536 + (size_t)(r0+q)*256 + c] = acc[q];
  } else {
    int j = threadIdx.x;
    if (j >= L || L + j >= 768) return;
    int r0 = (bx - 64) * 4;
    float* Vs = V + (size_t)s*768*256;
    float acc[4] = {0,0,0,0};
    for (int k = 0; k < 256; ++k){
      float v = Vs[(size_t)j*256 + k];
      #pragma unroll
      for (int q = 0; q < 4; ++q) acc[q] += A[(size_t)(r0+q)*256 + k] * v;
    }
    #pragma unroll
    for (int q = 0; q < 4; ++q) Vs[(size_t)(L+j)*256 + r0 + q] = acc[q];
  }
}

// Wt[s][i][col] with col = (kl*2+ri)*256 + o,  k = c8+kl
__global__ void k_wt(const float* __restrict__ wr, const float* __restrict__ wi,
                     float* __restrict__ Wt, int c8){
  int s = blockIdx.x, i = blockIdx.y, tid = threadIdx.x;
  size_t srcbase = ((size_t)s*256 + i)*256;
  float* dst = Wt + ((size_t)s*256 + i)*4096;
  for (int ph = 0; ph < 16; ++ph){
    int col = ph*256 + tid;
    int kl = col >> 9, ri = (col >> 8) & 1, o = col & 255;
    const float* src = ri ? wi : wr;
    dst[col] = src[(srcbase + o)*32 + c8 + kl];
  }
}

__device__ __forceinline__ void splitf16(float x, unsigned short &h, unsigned short &l){
  _Float16 hf = (_Float16)x;
  _Float16 lf = (_Float16)(x - (float)hf);
  h = __builtin_bit_cast(unsigned short, hf);
  l = __builtin_bit_cast(unsigned short, lf);
}
__device__ __forceinline__ unsigned int pk(unsigned short a, unsigned short b){
  return (unsigned int)a | ((unsigned int)b << 16);
}

// U = V @ Wt via fp16 split MFMA.  M in {192,384,768}, N=4096, K=256.
__global__ __launch_bounds__(256) void k_ugemm(const float* __restrict__ V,
                                               const float* __restrict__ Wt,
                                               float* __restrict__ U){
  int s = blockIdx.z;
  int Ts = 192 << s;
  int mt = blockIdx.y;
  if (mt*64 >= Ts) return;
  int nb = blockIdx.x * 64;
  const float* Vs = V + (size_t)s*768*256;
  const float* Bm = Wt + (size_t)s*256*4096;
  __shared__ unsigned int Ah[4*65*4], Al[4*65*4];
  __shared__ unsigned int Bh[4*65*4], Bl[4*65*4];
  int tid = threadIdx.x;
  int lane = tid & 63;
  int w = tid >> 6;
  int m0 = (w >> 1) * 32, n0 = (w & 1) * 32;
  int ml = lane & 15, quad = lane >> 4;
  f32x4 acc[2][2];
  #pragma unroll
  for (int t = 0; t < 2; ++t)
    #pragma unroll
    for (int u = 0; u < 2; ++u) acc[t][u] = (f32x4){0.f,0.f,0.f,0.f};

  int am = tid >> 2, akf = tid & 3;
  int bn = tid & 63, bq = tid >> 6;

  for (int kk = 0; kk < 8; ++kk){
    if (kk) __syncthreads();
    {
      const float* ap = &Vs[(size_t)(mt*64 + am)*256 + kk*32 + akf*8];
      float4 a0 = *(const float4*)ap;
      float4 a1 = *(const float4*)(ap + 4);
      unsigned short h[8], l[8];
      splitf16(a0.x*16.f, h[0], l[0]); splitf16(a0.y*16.f, h[1], l[1]);
      splitf16(a0.z*16.f, h[2], l[2]); splitf16(a0.w*16.f, h[3], l[3]);
      splitf16(a1.x*16.f, h[4], l[4]); splitf16(a1.y*16.f, h[5], l[5]);
      splitf16(a1.z*16.f, h[6], l[6]); splitf16(a1.w*16.f, h[7], l[7]);
      int base = (akf*65 + am)*4;
      *(uint4*)&Ah[base] = make_uint4(pk(h[0],h[1]), pk(h[2],h[3]), pk(h[4],h[5]), pk(h[6],h[7]));
      *(uint4*)&Al[base] = make_uint4(pk(l[0],l[1]), pk(l[2],l[3]), pk(l[4],l[5]), pk(l[6],l[7]));
    }
    {
      unsigned short h[8], l[8];
      #pragma unroll
      for (int j = 0; j < 8; ++j){
        float b = Bm[(size_t)(kk*32 + bq*8 + j)*4096 + nb + bn];
        splitf16(b*65536.f, h[j], l[j]);
      }
      int base = (bq*65 + bn)*4;
      *(uint4*)&Bh[base] = make_uint4(pk(h[0],h[1]), pk(h[2],h[3]), pk(h[4],h[5]), pk(h[6],h[7]));
      *(uint4*)&Bl[base] = make_uint4(pk(l[0],l[1]), pk(l[2],l[3]), pk(l[4],l[5]), pk(l[6],l[7]));
    }
    __syncthreads();
    half8 ah[2], al[2], bh[2], bl[2];
    #pragma unroll
    for (int t = 0; t < 2; ++t){
      int idx = (quad*65 + m0 + 16*t + ml)*4;
      ah[t] = *(const half8*)&Ah[idx];
      al[t] = *(const half8*)&Al[idx];
    }
    #pragma unroll
    for (int u = 0; u < 2; ++u){
      int idx = (quad*65 + n0 + 16*u + ml)*4;
      bh[u] = *(const half8*)&Bh[idx];
      bl[u] = *(const half8*)&Bl[idx];
    }
    #pragma unroll
    for (int t = 0; t < 2; ++t)
      #pragma unroll
      for (int u = 0; u < 2; ++u){
        acc[t][u] = __builtin_amdgcn_mfma_f32_16x16x32_f16(ah[t], bh[u], acc[t][u], 0, 0, 0);
        acc[t][u] = __builtin_amdgcn_mfma_f32_16x16x32_f16(ah[t], bl[u], acc[t][u], 0, 0, 0);
        acc[t][u] = __builtin_amdgcn_mfma_f32_16x16x32_f16(al[t], bh[u], acc[t][u], 0, 0, 0);
      }
  }
  int ub = (s == 0) ? 0 : (s == 1 ? 192 : 576);
  const float unscale = 1.0f / 1048576.0f;   // 2^-20
  #pragma unroll
  for (int t = 0; t < 2; ++t)
    #pragma unroll
    for (int u = 0; u < 2; ++u){
      int row = ub + mt*64 + m0 + 16*t + quad*4;
      int col = nb + n0 + 16*u + ml;
      #pragma unroll
      for (int r = 0; r < 4; ++r)
        U[(size_t)(row + r)*4096 + col] = acc[t][u][r] * unscale;
    }
}

// ---- two-phase parallel scan ----
__global__ void k_scanA(float* __restrict__ U, float* __restrict__ Seg, int c8){
  int seg = blockIdx.x;      // 0..7
  int kl  = blockIdx.y;      // 0..7
  int s   = blockIdx.z;      // 0..2
  int k = c8 + kl;
  int T = 192 << s;
  int Ls = T >> 3;
  int m0 = seg * Ls;
  int ub = (s == 0) ? 0 : (s == 1 ? 192 : 576);
  int o = threadIdx.x;
  float* Ur = U + ((size_t)(ub + m0))*4096 + kl*512 + o;
  float th = 6.283185307179586f / (float)T;
  int im = (k * m0) % T;
  float Zr = 0.f, Zi = 0.f;
  #pragma unroll 4
  for (int i = 0; i < Ls; ++i){
    float ur = Ur[0];
    float ui = Ur[256];
    float sa, ca; __sincosf(th * (float)im, &sa, &ca);
    Zr += ca*ur + sa*ui;
    Zi += ca*ui - sa*ur;
    Ur[0] = Zr; Ur[256] = Zi;
    im += k; if (im >= T) im -= T;
    Ur += 4096;
  }
  float* Sg = Seg + (((size_t)(s*8 + kl)*8 + seg)*2)*256 + o;
  Sg[0] = Zr; Sg[256] = Zi;
}

__global__ void k_scanC(const float* __restrict__ U, const float* __restrict__ Seg,
                        float* __restrict__ C8, int c8){
  int seg = blockIdx.x, kl = blockIdx.y, s = blockIdx.z;
  int k = c8 + kl;
  int T = 192 << s;
  int Ls = T >> 3;
  int m0 = seg * Ls;
  int ub = (s == 0) ? 0 : (s == 1 ? 192 : 576);
  int o = threadIdx.x;
  float offr = 0.f, offi = 0.f;
  const float* Sg = Seg + ((size_t)(s*8 + kl)*8)*512 + o;
  for (int j = 0; j < seg; ++j){ offr += Sg[(size_t)j*512]; offi += Sg[(size_t)j*512 + 256]; }
  const float* Ur = U + ((size_t)(ub + m0))*4096 + kl*512 + o;
  float* Cb = C8 + ((size_t)kl*1344 + ub)*256 + o;
  float ckT = ((k == 0) ? 1.0f : 2.0f) / (float)T;
  float th = 6.283185307179586f / (float)T;
  int ib = (k * (192 + m0)) % T;
  #pragma unroll 4
  for (int i = 0; i < Ls; ++i){
    int m = m0 + i;
    float zr = offr + Ur[0];
    float zi = offi + Ur[256];
    float sb, cb; __sincosf(th * (float)ib, &sb, &cb);
    Cb[(size_t)(T-1-m)*256] = ckT * (zr*cb - zi*sb);
    ib += k; if (ib >= T) ib -= T;
    Ur += 4096;
  }
}

// P[row][o] (+)= sum_kl C8[kl][row][o]
__global__ void k_reduce(const float* __restrict__ C8, float* __restrict__ P, int first){
  int row = blockIdx.x;    // 0..1343
  int o = threadIdx.x;
  float a = 0.f;
  #pragma unroll
  for (int kl = 0; kl < 8; ++kl) a += C8[((size_t)kl*1344 + row)*256 + o];
  size_t idx = (size_t)row*256 + o;
  if (first) P[idx] = a; else P[idx] += a;
}

// K[to][tg] = sum_s mlpw[s] * sum_o em[s][to][o] * P[s][tg-off][o]
// 64x64-tile LDS GEMM; scale column-ranges are whole 64-tiles (off = 576/384/0).
__global__ __launch_bounds__(256) void k_K(const float* __restrict__ em,
                                           const float* __restrict__ P,
                                           const float* __restrict__ mlpw,
                                           float* __restrict__ K){
  int tn = blockIdx.x;    // tg tile (12 x 64)
  int tmb = blockIdx.y;   // to tile (3 x 64)
  __shared__ float Es[16][68];
  __shared__ float Ps[16][68];
  int tid = threadIdx.x;
  int tm = tid >> 4, tnn = tid & 15;
  int srow = tid >> 2;
  int acol4 = (tid & 3) * 4;
  float acc[4][4];
  #pragma unroll
  for (int a = 0; a < 4; ++a)
    #pragma unroll
    for (int b = 0; b < 4; ++b) acc[a][b] = 0.f;
  for (int s = 0; s < 3; ++s){
    int T = 192 << s;
    int off = 768 - T;
    if (tn*64 < off) continue;
    int ub = (s == 0) ? 0 : (s == 1 ? 192 : 576);
    float mw = mlpw[s];
    const float* ems = em + ((size_t)s*192 + tmb*64)*256;
    const float* Pb = P + ((size_t)ub + (tn*64 - off))*256;
    float sacc[4][4];
    #pragma unroll
    for (int a = 0; a < 4; ++a)
      #pragma unroll
      for (int b = 0; b < 4; ++b) sacc[a][b] = 0.f;
    for (int k0 = 0; k0 < 256; k0 += 16){
      float4 e4 = *(const float4*)&ems[(size_t)srow*256 + k0 + acol4];
      Es[acol4+0][srow] = e4.x; Es[acol4+1][srow] = e4.y;
      Es[acol4+2][srow] = e4.z; Es[acol4+3][srow] = e4.w;
      float4 p4 = *(const float4*)&Pb[(size_t)srow*256 + k0 + acol4];
      Ps[acol4+0][srow] = p4.x; Ps[acol4+1][srow] = p4.y;
      Ps[acol4+2][srow] = p4.z; Ps[acol4+3][srow] = p4.w;
      __syncthreads();
      #pragma unroll
      for (int k = 0; k < 16; ++k){
        float av[4], bv[4];
        *(float4*)av = *(const float4*)&Es[k][tm*4];
        *(float4*)bv = *(const float4*)&Ps[k][tnn*4];
        #pragma unroll
        for (int a = 0; a < 4; ++a)
          #pragma unroll
          for (int b = 0; b < 4; ++b) sacc[a][b] += av[a]*bv[b];
      }
      __syncthreads();
    }
    #pragma unroll
    for (int a = 0; a < 4; ++a)
      #pragma unroll
      for (int b = 0; b < 4; ++b) acc[a][b] += mw * sacc[a][b];
  }
  int to0 = tmb*64 + tm*4;
  int tg0 = tn*64 + tnn*4;
  #pragma unroll
  for (int a = 0; a < 4; ++a){
    float4 o4 = make_float4(acc[a][0], acc[a][1], acc[a][2], acc[a][3]);
    *(float4*)&K[(size_t)(to0+a)*768 + tg0] = o4;
  }
}

// out[b][to][d] = mlp_b + sum_t K[to][t] * inputs[b][t][d]
__global__ __launch_bounds__(256) void k_out(const float* __restrict__ K,
                                             const float* __restrict__ inp,
                                             const float* __restrict__ mlpb,
                                             float* __restrict__ out){
  int to = blockIdx.x, b = blockIdx.y;
  int d = threadIdx.x & 63;
  int w = threadIdx.x >> 6;
  const float* Kr = K + (size_t)to*768 + w*192;
  const float* ip = inp + (size_t)b*768*64 + (size_t)(w*192)*64 + d;
  float acc = 0.f;
  #pragma unroll 4
  for (int i = 0; i < 192; ++i) acc += Kr[i] * ip[(size_t)i*64];
  __shared__ float red[4][64];
  red[w][d] = acc;
  __syncthreads();
  if (w == 0)
    out[((size_t)b*192 + to)*64 + d] =
      red[0][d] + red[1][d] + red[2][d] + red[3][d] + mlpb[0];
}

extern "C" void kernel_launch(void* const* d_in, const int* in_sizes, int n_in,
                              void* d_out, int out_size, void* d_ws, size_t ws_size,
                              hipStream_t stream){
  const float* inputs  = (const float*)d_in[0];
  const float* spec_wr = (const float*)d_in[1];
  const float* spec_wi = (const float*)d_in[2];
  const float* mlp_w   = (const float*)d_in[3];
  const float* mlp_b   = (const float*)d_in[4];
  float* out = (float*)d_out;
  char* ws = (char*)d_ws;

  double* Mf64 = (double*)(ws + OFF_MF64);
  double* Ya   = (double*)(ws + OFF_YA);
  double* Yb   = (double*)(ws + OFF_YB);
  double* Zb   = (double*)(ws + OFF_Z);
  float* W0  = (float*)(ws + OFF_W0);
  float* Fg  = (float*)(ws + OFF_F);
  int*   pivg= (int*)(ws + OFF_PIV);
  int*   usedg=(int*)(ws + OFF_USED);
  float* AP0 = (float*)(ws + OFF_AP0);
  float* AP1 = (float*)(ws + OFF_AP1);
  float* Bd  = (float*)(ws + OFF_BD);
  float* V   = (float*)(ws + OFF_V);
  float* em  = (float*)(ws + OFF_EM);
  float* P   = (float*)(ws + OFF_P);
  float* Km  = (float*)(ws + OFF_K);
  float* Wt  = (float*)(ws + OFF_WT);
  float* U   = (float*)(ws + OFF_U);
  float* C8  = (float*)(ws + OFF_C8);
  float* Seg = (float*)(ws + OFF_SEG);

  k_init<<<dim3(256,3), 256, 0, stream>>>(Mf64, W0, usedg);

  for (int kp = 0; kp < 8; ++kp){
    k_panelF<<<3, 256, 0, stream>>>(W0, Fg, pivg, usedg, kp);
    k_trailF<<<dim3(15-kp,3), 256, 0, stream>>>(W0, Fg, pivg, kp);
  }
  // right half now P*Minv; un-permute while lifting to f64
  k_y0<<<dim3(256,3), 256, 0, stream>>>(W0, pivg, Ya);
  for (int it = 0; it < 2; ++it){
    double* yi = (it & 1) ? Yb : Ya;
    double* yo = (it & 1) ? Ya : Yb;
    k_mmZ<<<dim3(32,3), 256, 0, stream>>>(Mf64, yi, Zb);
    k_mmN<<<dim3(32,3), 256, 0, stream>>>(yi, Zb, yo);
  }
  // refined Minv in Ya (2 Newton iters: Ya->Yb->Ya)
  k_final<<<dim3(65,3), 256, 0, stream>>>(Ya, AP0, Bd, V);
  k_em<<<3, 192, 0, stream>>>(em);

  // Krylov: doubling all the way (V[L..2L) = A^L V[0..L)); last level needs no square
  float* pin = AP0; float* pout = AP1;
  for (int L = 1; L <= 512; L <<= 1){
    k_level<<<dim3(128,3), 256, 0, stream>>>(pin, pout, V, L, (L == 512) ? 1 : 0);
    float* t = pin; pin = pout; pout = t;
  }

  for (int c = 0; c < 4; ++c){
    k_wt<<<dim3(3,256), 256, 0, stream>>>(spec_wr, spec_wi, Wt, c*8);
    k_ugemm<<<dim3(64,12,3), 256, 0, stream>>>(V, Wt, U);
    k_scanA<<<dim3(8,8,3), 256, 0, stream>>>(U, Seg, c*8);
    k_scanC<<<dim3(8,8,3), 256, 0, stream>>>(U, Seg, C8, c*8);
    k_reduce<<<1344, 256, 0, stream>>>(C8, P, (c == 0) ? 1 : 0);
  }
  k_K<<<dim3(12,192), 256, 0, stream>>>(em, P, mlp_w, Km);
  k_out<<<dim3(192,8), 256, 0, stream>>>(Km, inputs, mlp_b, out);
}

// Round 9
// 1102.352 us; speedup vs baseline: 1.0972x; 1.0972x over previous
//
#include <hip/hip_runtime.h>

// FiLM forward == fixed linear map K (192x768) applied to inputs (8,768,64), K rebuilt
// on-device each call from spec weights + HiPPO-LegT constants.
// Inversion: pivoted Gauss-Jordan with VIRTUAL pivoting (no row swaps; per-row used
// flags + recorded pivot sequence; right half ends as P*Minv, un-permuted in k_y0).
// Same arithmetic as classic partial pivoting -- LegT A is severely non-normal, so
// from-scratch Neumann/NS overflows f32 (round-3 lesson); GJ+f64 Newton is required.
// U-GEMM: fp16 2-way-split MFMA (16x16x32_f16, hh/hl/lh; exact 2^k scaling).
// K-GEMM: 64x64-tile LDS f32 GEMM, grid (12,3) -- round-9 fixes round-8's (12,192)
// launch-grid bug (189 garbage y-blocks, 80MB overfetch, 166us).
// Krylov: doubling all the way to L=512.
// Chunk-phase scratch C8/Seg alias the (dead by then) inversion/AP regions.

#define OFF_MF64  0
#define OFF_YA    1572864
#define OFF_YB    3145728
#define OFF_Z     4718592
#define OFF_W0    6291456     // [3][256][512] f32 augmented [M | I], in-place GJ
#define OFF_F     7864320     // [3][32][256] f32 per-panel elementary factors
#define OFF_PIV   7962624     // [3][256] int pivot sequence
#define OFF_USED  7966720     // [3][256] int used flags
#define OFF_AP0   10223616
#define OFF_AP1   11010048
#define OFF_BD    11796480
#define OFF_V     11800576
#define OFF_EM    14159872
#define OFF_P     14749696
#define OFF_K     16125952
#define OFF_WT    16715776
#define OFF_U     29298688
// aliases (live only during chunk phase; inversion/AP regions dead by then)
#define OFF_C8    0
#define OFF_SEG   11010048

typedef _Float16 half8 __attribute__((ext_vector_type(8)));
typedef float f32x4 __attribute__((ext_vector_type(4)));

__device__ __forceinline__ double a_entry(int i, int j){
  double base = (i < j) ? -1.0 : (((i - j) & 1) ? 1.0 : -1.0);  // (-1)^(i-j+1) for i>=j
  return base * (double)(2*i + 1);
}

// Build Mf64 = I - dt/2*A, GJ working buffer W0 = [M_f32 | I], zero used flags
__global__ void k_init(double* __restrict__ Mf64, float* __restrict__ W0,
                       int* __restrict__ usedg){
  int s = blockIdx.y, i = blockIdx.x, j = threadIdx.x;
  double dt = (1.0 / 192.0) / (double)(1 << s);
  double m = ((i == j) ? 1.0 : 0.0) - 0.5 * dt * a_entry(i, j);
  Mf64[((size_t)s*256 + i)*256 + j] = m;
  float* w = W0 + ((size_t)s*256 + i)*512;
  w[j] = (float)m;
  w[256 + j] = (i == j) ? 1.0f : 0.0f;
  if (j == 0) usedg[s*256 + i] = 0;
}

// Panel factorization, virtual pivoting: one row per thread in registers; argmax over
// unused rows; winner scales in place and publishes; F/pivots accumulate in registers.
__global__ __launch_bounds__(256) void k_panelF(const float* __restrict__ W0in,
                                                float* __restrict__ Fg,
                                                int* __restrict__ pivg,
                                                int* __restrict__ usedg, int kpanel){
  int s = blockIdx.x;
  const float* buf = W0in + (size_t)s*131072;
  float* Fb = Fg + (size_t)s*8192;
  int r = threadIdx.x;
  int c0 = kpanel*32;
  float row[32], freg[32];
  int pv[32];
  #pragma unroll
  for (int j = 0; j < 32; j += 4){
    float4 v = *(const float4*)&buf[(size_t)r*512 + c0 + j];
    row[j] = v.x; row[j+1] = v.y; row[j+2] = v.z; row[j+3] = v.w;
  }
  int used = usedg[s*256 + r];
  __shared__ float prow[2][32];
  __shared__ float wv[4];
  __shared__ int wi[4];
  #pragma unroll
  for (int l = 0; l < 32; ++l){
    float a = used ? -1.0f : fabsf(row[l]);
    int bi = r;
    #pragma unroll
    for (int off = 32; off > 0; off >>= 1){
      float oa = __shfl_xor(a, off);
      int ob = __shfl_xor(bi, off);
      if (oa > a || (oa == a && ob < bi)){ a = oa; bi = ob; }
    }
    if ((r & 63) == 0){ wv[r >> 6] = a; wi[r >> 6] = bi; }
    __syncthreads();
    float best = wv[0]; int piv = wi[0];
    #pragma unroll
    for (int w = 1; w < 4; ++w){
      if (wv[w] > best || (wv[w] == best && wi[w] < piv)){ best = wv[w]; piv = wi[w]; }
    }
    pv[l] = piv;
    if (r == piv){
      float inv = 1.0f / row[l];
      freg[l] = inv;
      used = 1;
      #pragma unroll
      for (int j = 0; j < 32; ++j){ row[j] *= inv; prow[l & 1][j] = row[j]; }
    }
    __syncthreads();
    float f = row[l];
    if (r != piv){
      freg[l] = f;
      #pragma unroll
      for (int j = 0; j < 32; ++j) row[j] -= f * prow[l & 1][j];
    }
  }
  #pragma unroll
  for (int l = 0; l < 32; ++l) Fb[l*256 + r] = freg[l];
  usedg[s*256 + r] = used;
  if (r == 0){
    #pragma unroll
    for (int l = 0; l < 32; ++l) pivg[s*256 + kpanel*32 + l] = pv[l];
  }
}

// Trailing update: replay the 32 elementary ops (virtual pivots) on a 32-col tile.
__global__ __launch_bounds__(256) void k_trailF(float* __restrict__ W0,
                                                const float* __restrict__ Fg,
                                                const int* __restrict__ pivg, int kpanel){
  int s = blockIdx.y;
  float* buf = W0 + (size_t)s*131072;
  const float* Fb = Fg + (size_t)s*8192;
  const int* pivb = pivg + s*256 + kpanel*32;
  int r = threadIdx.x;
  int col0 = 32*(kpanel+1) + blockIdx.x*32;
  float row[32], f[32];
  #pragma unroll
  for (int j = 0; j < 32; j += 4){
    float4 v = *(const float4*)&buf[(size_t)r*512 + col0 + j];
    row[j] = v.x; row[j+1] = v.y; row[j+2] = v.z; row[j+3] = v.w;
  }
  #pragma unroll
  for (int l = 0; l < 32; ++l) f[l] = Fb[l*256 + r];
  __shared__ float prow[2][32];
  __shared__ int pvs[32];
  if (r < 32) pvs[r] = pivb[r];
  __syncthreads();
  #pragma unroll
  for (int l = 0; l < 32; ++l){
    int piv = pvs[l];
    if (r == piv){
      #pragma unroll
      for (int j = 0; j < 32; ++j){ row[j] *= f[l]; prow[l & 1][j] = row[j]; }
    }
    __syncthreads();
    if (r != piv){
      #pragma unroll
      for (int j = 0; j < 32; ++j) row[j] -= f[l] * prow[l & 1][j];
    }
  }
  #pragma unroll
  for (int j = 0; j < 32; j += 4){
    float4 v = make_float4(row[j], row[j+1], row[j+2], row[j+3]);
    *(float4*)&buf[(size_t)r*512 + col0 + j] = v;
  }
}

// Y[l] = W0right[piv_l]  (un-permute: right half holds P*Minv)
__global__ void k_y0(const float* __restrict__ W, const int* __restrict__ pivg,
                     double* __restrict__ Y){
  int s = blockIdx.y, i = blockIdx.x, j = threadIdx.x;
  int p = pivg[s*256 + i];
  Y[((size_t)s*256 + i)*256 + j] = (double)W[((size_t)s*256 + p)*512 + 256 + j];
}

// Z = M @ Y  (f64)
__global__ void k_mmZ(const double* __restrict__ M, const double* __restrict__ Y,
                      double* __restrict__ Z){
  int s = blockIdx.y;
  const double* A = M + (size_t)s*65536;
  const double* B = Y + (size_t)s*65536;
  int c = threadIdx.x, r0 = blockIdx.x * 8;
  double acc[8] = {0,0,0,0,0,0,0,0};
  for (int j = 0; j < 256; ++j){
    double b = B[(size_t)j*256 + c];
    #pragma unroll
    for (int q = 0; q < 8; ++q) acc[q] += A[(size_t)(r0+q)*256 + j] * b;
  }
  #pragma unroll
  for (int q = 0; q < 8; ++q) Z[(size_t)s*65536 + (size_t)(r0+q)*256 + c] = acc[q];
}

// Yn = 2Y - Y @ Z  (Newton-Schulz step, f64)
__global__ void k_mmN(const double* __restrict__ Y, const double* __restrict__ Z,
                      double* __restrict__ Yn){
  int s = blockIdx.y;
  const double* A = Y + (size_t)s*65536;
  const double* B = Z + (size_t)s*65536;
  int c = threadIdx.x, r0 = blockIdx.x * 8;
  double acc[8] = {0,0,0,0,0,0,0,0};
  for (int j = 0; j < 256; ++j){
    double b = B[(size_t)j*256 + c];
    #pragma unroll
    for (int q = 0; q < 8; ++q) acc[q] += A[(size_t)(r0+q)*256 + j] * b;
  }
  #pragma unroll
  for (int q = 0; q < 8; ++q)
    Yn[(size_t)s*65536 + (size_t)(r0+q)*256 + c] =
      2.0 * A[(size_t)(r0+q)*256 + c] - acc[q];
}

// Ad = 2*Minv - I (f32, into AP0); Bd = Minv @ (dt*B); V row0 = Bd
__global__ void k_final(const double* __restrict__ Y, float* __restrict__ Ad,
                        float* __restrict__ Bd, float* __restrict__ V){
  int s = blockIdx.y;
  const double* Ys = Y + (size_t)s*65536;
  if (blockIdx.x < 64){
    int c = threadIdx.x, r0 = blockIdx.x * 4;
    #pragma unroll
    for (int q = 0; q < 4; ++q){
      double v = 2.0 * Ys[(size_t)(r0+q)*256 + c] - ((r0+q) == c ? 1.0 : 0.0);
      Ad[(size_t)s*65536 + (size_t)(r0+q)*256 + c] = (float)v;
    }
  } else {
    int i = threadIdx.x;
    double dt = (1.0 / 192.0) / (double)(1 << s);
    double acc = 0.0;
    for (int j = 0; j < 256; ++j){
      double bj = dt * ((j & 1) ? -1.0 : 1.0) * (double)(2*j + 1);
      acc += Ys[(size_t)i*256 + j] * bj;
    }
    float b = (float)acc;
    Bd[s*256 + i] = b;
    V[((size_t)s*768 + 0)*256 + i] = b;
  }
}

// Legendre eval matrix (last 192 rows), f64 recurrence
__global__ void k_em(float* __restrict__ em){
  int s = blockIdx.x, t = threadIdx.x;
  int T = 192 << s;
  double dt = (1.0 / 192.0) / (double)(1 << s);
  double x = 1.0 - 2.0 * ((double)(T - 192 + t) * dt);
  float* row = em + ((size_t)s*192 + t)*256;
  double p0 = 1.0, p1 = x;
  row[0] = 1.0f; row[1] = (float)x;
  for (int n = 1; n < 255; ++n){
    double p2 = ((double)(2*n+1) * x * p1 - (double)n * p0) / (double)(n+1);
    row[n+1] = (float)p2;
    p0 = p1; p1 = p2;
  }
}

// one doubling level: Pout = Pin@Pin (bx<64, skipped if noSquare);
// V[L..min(2L,768)) = Pin @ V[0..L) (bx>=64)
__global__ void k_level(const float* __restrict__ Pin, float* __restrict__ Pout,
                        float* __restrict__ V, int L, int noSquare){
  int s = blockIdx.y;
  const float* A = Pin + (size_t)s*65536;
  int bx = blockIdx.x;
  if (bx < 64){
    if (noSquare) return;
    int c = threadIdx.x, r0 = bx * 4;
    float acc[4] = {0,0,0,0};
    for (int k = 0; k < 256; ++k){
      float b = A[(size_t)k*256 + c];
      #pragma unroll
      for (int q = 0; q < 4; ++q) acc[q] += A[(size_t)(r0+q)*256 + k] * b;
    }
    #pragma unroll
    for (int q = 0; q < 4; ++q) Pout[(size_t)s*65536 + (size_t)(r0+q)*256 + c] = acc[q];
  } else {
    int j = threadIdx.x;
    if (j >= L || L + j >= 768) return;
    int r0 = (bx - 64) * 4;
    float* Vs = V + (size_t)s*768*256;
    float acc[4] = {0,0,0,0};
    for (int k = 0; k < 256; ++k){
      float v = Vs[(size_t)j*256 + k];
      #pragma unroll
      for (int q = 0; q < 4; ++q) acc[q] += A[(size_t)(r0+q)*256 + k] * v;
    }
    #pragma unroll
    for (int q = 0; q < 4; ++q) Vs[(size_t)(L+j)*256 + r0 + q] = acc[q];
  }
}

// Wt[s][i][col] with col = (kl*2+ri)*256 + o,  k = c8+kl
__global__ void k_wt(const float* __restrict__ wr, const float* __restrict__ wi,
                     float* __restrict__ Wt, int c8){
  int s = blockIdx.x, i = blockIdx.y, tid = threadIdx.x;
  size_t srcbase = ((size_t)s*256 + i)*256;
  float* dst = Wt + ((size_t)s*256 + i)*4096;
  for (int ph = 0; ph < 16; ++ph){
    int col = ph*256 + tid;
    int kl = col >> 9, ri = (col >> 8) & 1, o = col & 255;
    const float* src = ri ? wi : wr;
    dst[col] = src[(srcbase + o)*32 + c8 + kl];
  }
}

__device__ __forceinline__ void splitf16(float x, unsigned short &h, unsigned short &l){
  _Float16 hf = (_Float16)x;
  _Float16 lf = (_Float16)(x - (float)hf);
  h = __builtin_bit_cast(unsigned short, hf);
  l = __builtin_bit_cast(unsigned short, lf);
}
__device__ __forceinline__ unsigned int pk(unsigned short a, unsigned short b){
  return (unsigned int)a | ((unsigned int)b << 16);
}

// U = V @ Wt via fp16 split MFMA.  M in {192,384,768}, N=4096, K=256.
__global__ __launch_bounds__(256) void k_ugemm(const float* __restrict__ V,
                                               const float* __restrict__ Wt,
                                               float* __restrict__ U){
  int s = blockIdx.z;
  int Ts = 192 << s;
  int mt = blockIdx.y;
  if (mt*64 >= Ts) return;
  int nb = blockIdx.x * 64;
  const float* Vs = V + (size_t)s*768*256;
  const float* Bm = Wt + (size_t)s*256*4096;
  __shared__ unsigned int Ah[4*65*4], Al[4*65*4];
  __shared__ unsigned int Bh[4*65*4], Bl[4*65*4];
  int tid = threadIdx.x;
  int lane = tid & 63;
  int w = tid >> 6;
  int m0 = (w >> 1) * 32, n0 = (w & 1) * 32;
  int ml = lane & 15, quad = lane >> 4;
  f32x4 acc[2][2];
  #pragma unroll
  for (int t = 0; t < 2; ++t)
    #pragma unroll
    for (int u = 0; u < 2; ++u) acc[t][u] = (f32x4){0.f,0.f,0.f,0.f};

  int am = tid >> 2, akf = tid & 3;
  int bn = tid & 63, bq = tid >> 6;

  for (int kk = 0; kk < 8; ++kk){
    if (kk) __syncthreads();
    {
      const float* ap = &Vs[(size_t)(mt*64 + am)*256 + kk*32 + akf*8];
      float4 a0 = *(const float4*)ap;
      float4 a1 = *(const float4*)(ap + 4);
      unsigned short h[8], l[8];
      splitf16(a0.x*16.f, h[0], l[0]); splitf16(a0.y*16.f, h[1], l[1]);
      splitf16(a0.z*16.f, h[2], l[2]); splitf16(a0.w*16.f, h[3], l[3]);
      splitf16(a1.x*16.f, h[4], l[4]); splitf16(a1.y*16.f, h[5], l[5]);
      splitf16(a1.z*16.f, h[6], l[6]); splitf16(a1.w*16.f, h[7], l[7]);
      int base = (akf*65 + am)*4;
      *(uint4*)&Ah[base] = make_uint4(pk(h[0],h[1]), pk(h[2],h[3]), pk(h[4],h[5]), pk(h[6],h[7]));
      *(uint4*)&Al[base] = make_uint4(pk(l[0],l[1]), pk(l[2],l[3]), pk(l[4],l[5]), pk(l[6],l[7]));
    }
    {
      unsigned short h[8], l[8];
      #pragma unroll
      for (int j = 0; j < 8; ++j){
        float b = Bm[(size_t)(kk*32 + bq*8 + j)*4096 + nb + bn];
        splitf16(b*65536.f, h[j], l[j]);
      }
      int base = (bq*65 + bn)*4;
      *(uint4*)&Bh[base] = make_uint4(pk(h[0],h[1]), pk(h[2],h[3]), pk(h[4],h[5]), pk(h[6],h[7]));
      *(uint4*)&Bl[base] = make_uint4(pk(l[0],l[1]), pk(l[2],l[3]), pk(l[4],l[5]), pk(l[6],l[7]));
    }
    __syncthreads();
    half8 ah[2], al[2], bh[2], bl[2];
    #pragma unroll
    for (int t = 0; t < 2; ++t){
      int idx = (quad*65 + m0 + 16*t + ml)*4;
      ah[t] = *(const half8*)&Ah[idx];
      al[t] = *(const half8*)&Al[idx];
    }
    #pragma unroll
    for (int u = 0; u < 2; ++u){
      int idx = (quad*65 + n0 + 16*u + ml)*4;
      bh[u] = *(const half8*)&Bh[idx];
      bl[u] = *(const half8*)&Bl[idx];
    }
    #pragma unroll
    for (int t = 0; t < 2; ++t)
      #pragma unroll
      for (int u = 0; u < 2; ++u){
        acc[t][u] = __builtin_amdgcn_mfma_f32_16x16x32_f16(ah[t], bh[u], acc[t][u], 0, 0, 0);
        acc[t][u] = __builtin_amdgcn_mfma_f32_16x16x32_f16(ah[t], bl[u], acc[t][u], 0, 0, 0);
        acc[t][u] = __builtin_amdgcn_mfma_f32_16x16x32_f16(al[t], bh[u], acc[t][u], 0, 0, 0);
      }
  }
  int ub = (s == 0) ? 0 : (s == 1 ? 192 : 576);
  const float unscale = 1.0f / 1048576.0f;   // 2^-20
  #pragma unroll
  for (int t = 0; t < 2; ++t)
    #pragma unroll
    for (int u = 0; u < 2; ++u){
      int row = ub + mt*64 + m0 + 16*t + quad*4;
      int col = nb + n0 + 16*u + ml;
      #pragma unroll
      for (int r = 0; r < 4; ++r)
        U[(size_t)(row + r)*4096 + col] = acc[t][u][r] * unscale;
    }
}

// ---- two-phase parallel scan ----
__global__ void k_scanA(float* __restrict__ U, float* __restrict__ Seg, int c8){
  int seg = blockIdx.x;      // 0..7
  int kl  = blockIdx.y;      // 0..7
  int s   = blockIdx.z;      // 0..2
  int k = c8 + kl;
  int T = 192 << s;
  int Ls = T >> 3;
  int m0 = seg * Ls;
  int ub = (s == 0) ? 0 : (s == 1 ? 192 : 576);
  int o = threadIdx.x;
  float* Ur = U + ((size_t)(ub + m0))*4096 + kl*512 + o;
  float th = 6.283185307179586f / (float)T;
  int im = (k * m0) % T;
  float Zr = 0.f, Zi = 0.f;
  #pragma unroll 4
  for (int i = 0; i < Ls; ++i){
    float ur = Ur[0];
    float ui = Ur[256];
    float sa, ca; __sincosf(th * (float)im, &sa, &ca);
    Zr += ca*ur + sa*ui;
    Zi += ca*ui - sa*ur;
    Ur[0] = Zr; Ur[256] = Zi;
    im += k; if (im >= T) im -= T;
    Ur += 4096;
  }
  float* Sg = Seg + (((size_t)(s*8 + kl)*8 + seg)*2)*256 + o;
  Sg[0] = Zr; Sg[256] = Zi;
}

__global__ void k_scanC(const float* __restrict__ U, const float* __restrict__ Seg,
                        float* __restrict__ C8, int c8){
  int seg = blockIdx.x, kl = blockIdx.y, s = blockIdx.z;
  int k = c8 + kl;
  int T = 192 << s;
  int Ls = T >> 3;
  int m0 = seg * Ls;
  int ub = (s == 0) ? 0 : (s == 1 ? 192 : 576);
  int o = threadIdx.x;
  float offr = 0.f, offi = 0.f;
  const float* Sg = Seg + ((size_t)(s*8 + kl)*8)*512 + o;
  for (int j = 0; j < seg; ++j){ offr += Sg[(size_t)j*512]; offi += Sg[(size_t)j*512 + 256]; }
  const float* Ur = U + ((size_t)(ub + m0))*4096 + kl*512 + o;
  float* Cb = C8 + ((size_t)kl*1344 + ub)*256 + o;
  float ckT = ((k == 0) ? 1.0f : 2.0f) / (float)T;
  float th = 6.283185307179586f / (float)T;
  int ib = (k * (192 + m0)) % T;
  #pragma unroll 4
  for (int i = 0; i < Ls; ++i){
    int m = m0 + i;
    float zr = offr + Ur[0];
    float zi = offi + Ur[256];
    float sb, cb; __sincosf(th * (float)ib, &sb, &cb);
    Cb[(size_t)(T-1-m)*256] = ckT * (zr*cb - zi*sb);
    ib += k; if (ib >= T) ib -= T;
    Ur += 4096;
  }
}

// P[row][o] (+)= sum_kl C8[kl][row][o]
__global__ void k_reduce(const float* __restrict__ C8, float* __restrict__ P, int first){
  int row = blockIdx.x;    // 0..1343
  int o = threadIdx.x;
  float a = 0.f;
  #pragma unroll
  for (int kl = 0; kl < 8; ++kl) a += C8[((size_t)kl*1344 + row)*256 + o];
  size_t idx = (size_t)row*256 + o;
  if (first) P[idx] = a; else P[idx] += a;
}

// K[to][tg] = sum_s mlpw[s] * sum_o em[s][to][o] * P[s][tg-off][o]
// 64x64-tile LDS GEMM; grid MUST be (12, 3): y = 64-row to-tile.
__global__ __launch_bounds__(256) void k_K(const float* __restrict__ em,
                                           const float* __restrict__ P,
                                           const float* __restrict__ mlpw,
                                           float* __restrict__ K){
  int tn = blockIdx.x;    // tg tile (12 x 64)
  int tmb = blockIdx.y;   // to tile (3 x 64)
  __shared__ float Es[16][68];
  __shared__ float Ps[16][68];
  int tid = threadIdx.x;
  int tm = tid >> 4, tnn = tid & 15;
  int srow = tid >> 2;
  int acol4 = (tid & 3) * 4;
  float acc[4][4];
  #pragma unroll
  for (int a = 0; a < 4; ++a)
    #pragma unroll
    for (int b = 0; b < 4; ++b) acc[a][b] = 0.f;
  for (int s = 0; s < 3; ++s){
    int T = 192 << s;
    int off = 768 - T;
    if (tn*64 < off) continue;
    int ub = (s == 0) ? 0 : (s == 1 ? 192 : 576);
    float mw = mlpw[s];
    const float* ems = em + ((size_t)s*192 + tmb*64)*256;
    const float* Pb = P + ((size_t)ub + (tn*64 - off))*256;
    float sacc[4][4];
    #pragma unroll
    for (int a = 0; a < 4; ++a)
      #pragma unroll
      for (int b = 0; b < 4; ++b) sacc[a][b] = 0.f;
    for (int k0 = 0; k0 < 256; k0 += 16){
      float4 e4 = *(const float4*)&ems[(size_t)srow*256 + k0 + acol4];
      Es[acol4+0][srow] = e4.x; Es[acol4+1][srow] = e4.y;
      Es[acol4+2][srow] = e4.z; Es[acol4+3][srow] = e4.w;
      float4 p4 = *(const float4*)&Pb[(size_t)srow*256 + k0 + acol4];
      Ps[acol4+0][srow] = p4.x; Ps[acol4+1][srow] = p4.y;
      Ps[acol4+2][srow] = p4.z; Ps[acol4+3][srow] = p4.w;
      __syncthreads();
      #pragma unroll
      for (int k = 0; k < 16; ++k){
        float av[4], bv[4];
        *(float4*)av = *(const float4*)&Es[k][tm*4];
        *(float4*)bv = *(const float4*)&Ps[k][tnn*4];
        #pragma unroll
        for (int a = 0; a < 4; ++a)
          #pragma unroll
          for (int b = 0; b < 4; ++b) sacc[a][b] += av[a]*bv[b];
      }
      __syncthreads();
    }
    #pragma unroll
    for (int a = 0; a < 4; ++a)
      #pragma unroll
      for (int b = 0; b < 4; ++b) acc[a][b] += mw * sacc[a][b];
  }
  int to0 = tmb*64 + tm*4;
  int tg0 = tn*64 + tnn*4;
  #pragma unroll
  for (int a = 0; a < 4; ++a){
    float4 o4 = make_float4(acc[a][0], acc[a][1], acc[a][2], acc[a][3]);
    *(float4*)&K[(size_t)(to0+a)*768 + tg0] = o4;
  }
}

// out[b][to][d] = mlp_b + sum_t K[to][t] * inputs[b][t][d]
__global__ __launch_bounds__(256) void k_out(const float* __restrict__ K,
                                             const float* __restrict__ inp,
                                             const float* __restrict__ mlpb,
                                             float* __restrict__ out){
  int to = blockIdx.x, b = blockIdx.y;
  int d = threadIdx.x & 63;
  int w = threadIdx.x >> 6;
  const float* Kr = K + (size_t)to*768 + w*192;
  const float* ip = inp + (size_t)b*768*64 + (size_t)(w*192)*64 + d;
  float acc = 0.f;
  #pragma unroll 4
  for (int i = 0; i < 192; ++i) acc += Kr[i] * ip[(size_t)i*64];
  __shared__ float red[4][64];
  red[w][d] = acc;
  __syncthreads();
  if (w == 0)
    out[((size_t)b*192 + to)*64 + d] =
      red[0][d] + red[1][d] + red[2][d] + red[3][d] + mlpb[0];
}

extern "C" void kernel_launch(void* const* d_in, const int* in_sizes, int n_in,
                              void* d_out, int out_size, void* d_ws, size_t ws_size,
                              hipStream_t stream){
  const float* inputs  = (const float*)d_in[0];
  const float* spec_wr = (const float*)d_in[1];
  const float* spec_wi = (const float*)d_in[2];
  const float* mlp_w   = (const float*)d_in[3];
  const float* mlp_b   = (const float*)d_in[4];
  float* out = (float*)d_out;
  char* ws = (char*)d_ws;

  double* Mf64 = (double*)(ws + OFF_MF64);
  double* Ya   = (double*)(ws + OFF_YA);
  double* Yb   = (double*)(ws + OFF_YB);
  double* Zb   = (double*)(ws + OFF_Z);
  float* W0  = (float*)(ws + OFF_W0);
  float* Fg  = (float*)(ws + OFF_F);
  int*   pivg= (int*)(ws + OFF_PIV);
  int*   usedg=(int*)(ws + OFF_USED);
  float* AP0 = (float*)(ws + OFF_AP0);
  float* AP1 = (float*)(ws + OFF_AP1);
  float* Bd  = (float*)(ws + OFF_BD);
  float* V   = (float*)(ws + OFF_V);
  float* em  = (float*)(ws + OFF_EM);
  float* P   = (float*)(ws + OFF_P);
  float* Km  = (float*)(ws + OFF_K);
  float* Wt  = (float*)(ws + OFF_WT);
  float* U   = (float*)(ws + OFF_U);
  float* C8  = (float*)(ws + OFF_C8);
  float* Seg = (float*)(ws + OFF_SEG);

  k_init<<<dim3(256,3), 256, 0, stream>>>(Mf64, W0, usedg);

  for (int kp = 0; kp < 8; ++kp){
    k_panelF<<<3, 256, 0, stream>>>(W0, Fg, pivg, usedg, kp);
    k_trailF<<<dim3(15-kp,3), 256, 0, stream>>>(W0, Fg, pivg, kp);
  }
  // right half now P*Minv; un-permute while lifting to f64
  k_y0<<<dim3(256,3), 256, 0, stream>>>(W0, pivg, Ya);
  for (int it = 0; it < 2; ++it){
    double* yi = (it & 1) ? Yb : Ya;
    double* yo = (it & 1) ? Ya : Yb;
    k_mmZ<<<dim3(32,3), 256, 0, stream>>>(Mf64, yi, Zb);
    k_mmN<<<dim3(32,3), 256, 0, stream>>>(yi, Zb, yo);
  }
  // refined Minv in Ya (2 Newton iters: Ya->Yb->Ya)
  k_final<<<dim3(65,3), 256, 0, stream>>>(Ya, AP0, Bd, V);
  k_em<<<3, 192, 0, stream>>>(em);

  // Krylov: doubling all the way (V[L..2L) = A^L V[0..L)); last level needs no square
  float* pin = AP0; float* pout = AP1;
  for (int L = 1; L <= 512; L <<= 1){
    k_level<<<dim3(128,3), 256, 0, stream>>>(pin, pout, V, L, (L == 512) ? 1 : 0);
    float* t = pin; pin = pout; pout = t;
  }

  for (int c = 0; c < 4; ++c){
    k_wt<<<dim3(3,256), 256, 0, stream>>>(spec_wr, spec_wi, Wt, c*8);
    k_ugemm<<<dim3(64,12,3), 256, 0, stream>>>(V, Wt, U);
    k_scanA<<<dim3(8,8,3), 256, 0, stream>>>(U, Seg, c*8);
    k_scanC<<<dim3(8,8,3), 256, 0, stream>>>(U, Seg, C8, c*8);
    k_reduce<<<1344, 256, 0, stream>>>(C8, P, (c == 0) ? 1 : 0);
  }
  k_K<<<dim3(12,3), 256, 0, stream>>>(em, P, mlp_w, Km);
  k_out<<<dim3(192,8), 256, 0, stream>>>(Km, inputs, mlp_b, out);
}

// Round 10
// 821.064 us; speedup vs baseline: 1.4731x; 1.3426x over previous
//
#include <hip/hip_runtime.h>

// FiLM forward == fixed linear map K (192x768) applied to inputs (8,768,64), K rebuilt
// on-device each call from spec weights + HiPPO-LegT constants.
// Inversion: pivoted Gauss-Jordan, FUSED single kernel (k_gj): 48 blocks = 3 scales x
// 16 col-groups; factor block publishes F/pivots via device-scope release flag;
// replay blocks spin-acquire. DPP-chain wave argmax (update_dpp) replaces ds_swizzle
// butterfly. Virtual pivoting (no row swaps); right half ends P*Minv, un-permuted in
// k_y0; 2 batched f64 Newton polish iterations after.
// U-GEMM: fp16 2-way-split MFMA (16x16x32_f16, hh/hl/lh; exact 2^k scaling).
// Chunk phase: ALL 32 modes in one pass (ws is 256MiB: U4=88MB, Wt4=50MB, C32=44MB).

#define OFF_MF64  0
#define OFF_YA    1572864
#define OFF_YB    3145728
#define OFF_Z     4718592
#define OFF_W0    6291456     // [3][256][512] f32; only right half written/used
#define OFF_F     7864320     // [3][8][32][256] f32 per-panel factors
#define OFF_PIV   8650752     // [3][256] int pivot sequence
#define OFF_FLAG  8653824     // [3][8] int panel-ready flags
#define OFF_AP0   10223616
#define OFF_AP1   11010048
#define OFF_BD    11796480
#define OFF_V     11800576
#define OFF_EM    14159872
#define OFF_P     14749696
#define OFF_K     16125952
#define OFF_U4    29298688    // [1344][16384] f32 = 88.1 MB
#define OFF_WT4   117440512   // [3][256][16384] f32 = 50.3 MB
#define OFF_C32   167772160   // [32][1344][256] f32 = 44.0 MB
#define OFF_SEG4  211812352   // [3][32][8][2][256] f32 = 1.5 MB

typedef _Float16 half8 __attribute__((ext_vector_type(8)));
typedef float f32x4 __attribute__((ext_vector_type(4)));

__device__ __forceinline__ double a_entry(int i, int j){
  double base = (i < j) ? -1.0 : (((i - j) & 1) ? 1.0 : -1.0);  // (-1)^(i-j+1) for i>=j
  return base * (double)(2*i + 1);
}

// wave64 unsigned-max reduce via DPP; result valid in lane 63 of each wave.
__device__ __forceinline__ unsigned int dpp_umax(unsigned int x){
  unsigned int t;
  t = (unsigned int)__builtin_amdgcn_update_dpp((int)x, (int)x, 0x111, 0xF, 0xF, false); x = x > t ? x : t;
  t = (unsigned int)__builtin_amdgcn_update_dpp((int)x, (int)x, 0x112, 0xF, 0xF, false); x = x > t ? x : t;
  t = (unsigned int)__builtin_amdgcn_update_dpp((int)x, (int)x, 0x114, 0xF, 0xE, false); x = x > t ? x : t;
  t = (unsigned int)__builtin_amdgcn_update_dpp((int)x, (int)x, 0x118, 0xF, 0xC, false); x = x > t ? x : t;
  t = (unsigned int)__builtin_amdgcn_update_dpp((int)x, (int)x, 0x142, 0xA, 0xF, false); x = x > t ? x : t;
  t = (unsigned int)__builtin_amdgcn_update_dpp((int)x, (int)x, 0x143, 0xC, 0xF, false); x = x > t ? x : t;
  return x;
}

// Mf64 = I - dt/2*A; em (Legendre eval rows, f64 recurrence); zero panel flags.
__global__ void k_init(double* __restrict__ Mf64, float* __restrict__ em,
                       int* __restrict__ flags){
  int s = blockIdx.y, i = blockIdx.x, j = threadIdx.x;
  if (i < 256){
    double dt = (1.0 / 192.0) / (double)(1 << s);
    double m = ((i == j) ? 1.0 : 0.0) - 0.5 * dt * a_entry(i, j);
    Mf64[((size_t)s*256 + i)*256 + j] = m;
  } else {
    if (j < 192){
      int T = 192 << s;
      double dt = (1.0 / 192.0) / (double)(1 << s);
      double x = 1.0 - 2.0 * ((double)(T - 192 + j) * dt);
      float* row = em + ((size_t)s*192 + j)*256;
      double p0 = 1.0, p1 = x;
      row[0] = 1.0f; row[1] = (float)x;
      for (int n = 1; n < 255; ++n){
        double p2 = ((double)(2*n+1) * x * p1 - (double)n * p0) / (double)(n+1);
        row[n+1] = (float)p2;
        p0 = p1; p1 = p2;
      }
    } else if (j < 200){
      flags[s*8 + (j - 192)] = 0;
    }
  }
}

// Fused pivoted Gauss-Jordan. Block (s,g): cols [32g,32g+32) of [M | I].
// g<8: replay panels 0..g-1 then factor panel g (publish F+piv, release flag).
// g>=8: replay all 8 panels, then write tile to W0 right half.
__global__ __launch_bounds__(256) void k_gj(float* __restrict__ W0,
                                            float* __restrict__ Fg,
                                            int* __restrict__ pivg,
                                            int* __restrict__ flags){
  int s = blockIdx.x >> 4;
  int g = blockIdx.x & 15;
  int r = threadIdx.x;
  int c0 = g*32;
  float row[32];
  if (g < 8){
    double dt = (1.0 / 192.0) / (double)(1 << s);
    #pragma unroll
    for (int j = 0; j < 32; ++j){
      int col = c0 + j;
      row[j] = (float)(((r == col) ? 1.0 : 0.0) - 0.5*dt*a_entry(r, col));
    }
  } else {
    #pragma unroll
    for (int j = 0; j < 32; ++j) row[j] = (r == c0 - 256 + j) ? 1.f : 0.f;
  }
  __shared__ float Fl[32*256];
  __shared__ float prow[2][32];
  __shared__ float prow1[32];
  __shared__ int pvs[32];
  __shared__ unsigned int wv[4];
  __shared__ float sInvS;
  int used = 0;
  int* flagS = flags + s*8;
  int nrep = (g < 8) ? g : 8;
  for (int kp = 0; kp < nrep; ++kp){
    if (r == 0){
      int cnt = 0;
      while (__hip_atomic_load(&flagS[kp], __ATOMIC_ACQUIRE, __HIP_MEMORY_SCOPE_AGENT) == 0){
        __builtin_amdgcn_s_sleep(8);
        if (++cnt > 100000000) break;
      }
    }
    __syncthreads();
    const float* Fp = Fg + ((size_t)(s*8 + kp))*8192;
    #pragma unroll
    for (int l = 0; l < 32; ++l) Fl[l*256 + r] = Fp[l*256 + r];
    if (r < 32) pvs[r] = pivg[s*256 + kp*32 + r];
    __syncthreads();
    #pragma unroll
    for (int l = 0; l < 32; ++l) if (pvs[l] == r) used = 1;
    for (int l = 0; l < 32; ++l){
      int piv = pvs[l];
      float fv = Fl[l*256 + r];
      if (r == piv){
        #pragma unroll
        for (int j = 0; j < 32; ++j){ row[j] *= fv; prow[l & 1][j] = row[j]; }
      }
      __syncthreads();
      if (r != piv){
        #pragma unroll
        for (int j = 0; j < 32; ++j) row[j] -= fv * prow[l & 1][j];
      }
    }
    __syncthreads();
  }
  if (g < 8){
    float* Fgp = Fg + ((size_t)(s*8 + g))*8192;
    #pragma unroll
    for (int l = 0; l < 32; ++l){
      float av = fabsf(row[l]);
      unsigned int kb = __builtin_bit_cast(unsigned int, av);
      unsigned int key = used ? 0u : ((kb & 0xFFFFFF00u) | (unsigned int)(255 - r));
      key = dpp_umax(key);
      if ((r & 63) == 63) wv[r >> 6] = key;
      __syncthreads();
      unsigned int b0 = wv[0] > wv[1] ? wv[0] : wv[1];
      unsigned int b1 = wv[2] > wv[3] ? wv[2] : wv[3];
      unsigned int best = b0 > b1 ? b0 : b1;
      int piv = 255 - (int)(best & 0xFFu);
      if (r == piv){
        float inv = 1.0f / row[l];
        sInvS = inv;
        used = 1;
        #pragma unroll
        for (int j = 0; j < 32; ++j){ row[j] *= inv; prow1[j] = row[j]; }
      }
      if (r == 0) pvs[l] = piv;
      __syncthreads();
      float f = (r == piv) ? 0.0f : row[l];
      Fgp[l*256 + r] = (r == piv) ? sInvS : f;
      if (r != piv){
        #pragma unroll
        for (int j = 0; j < 32; ++j) row[j] -= f * prow1[j];
      }
    }
    if (r < 32) pivg[s*256 + g*32 + r] = pvs[r];
    __threadfence();
    __syncthreads();
    if (r == 0)
      __hip_atomic_store(&flagS[g], 1, __ATOMIC_RELEASE, __HIP_MEMORY_SCOPE_AGENT);
  } else {
    float* buf = W0 + (size_t)s*131072;
    #pragma unroll
    for (int j = 0; j < 32; j += 4){
      float4 v = make_float4(row[j], row[j+1], row[j+2], row[j+3]);
      *(float4*)&buf[(size_t)r*512 + c0 + j] = v;
    }
  }
}

// Y[i] = W0right[piv_i]  (un-permute: right half holds P*Minv)
__global__ void k_y0(const float* __restrict__ W, const int* __restrict__ pivg,
                     double* __restrict__ Y){
  int s = blockIdx.y, i = blockIdx.x, j = threadIdx.x;
  int p = pivg[s*256 + i];
  Y[((size_t)s*256 + i)*256 + j] = (double)W[((size_t)s*256 + p)*512 + 256 + j];
}

// Z = M @ Y  (f64)
__global__ void k_mmZ(const double* __restrict__ M, const double* __restrict__ Y,
                      double* __restrict__ Z){
  int s = blockIdx.y;
  const double* A = M + (size_t)s*65536;
  const double* B = Y + (size_t)s*65536;
  int c = threadIdx.x, r0 = blockIdx.x * 8;
  double acc[8] = {0,0,0,0,0,0,0,0};
  for (int j = 0; j < 256; ++j){
    double b = B[(size_t)j*256 + c];
    #pragma unroll
    for (int q = 0; q < 8; ++q) acc[q] += A[(size_t)(r0+q)*256 + j] * b;
  }
  #pragma unroll
  for (int q = 0; q < 8; ++q) Z[(size_t)s*65536 + (size_t)(r0+q)*256 + c] = acc[q];
}

// Yn = 2Y - Y @ Z  (Newton-Schulz step, f64)
__global__ void k_mmN(const double* __restrict__ Y, const double* __restrict__ Z,
                      double* __restrict__ Yn){
  int s = blockIdx.y;
  const double* A = Y + (size_t)s*65536;
  const double* B = Z + (size_t)s*65536;
  int c = threadIdx.x, r0 = blockIdx.x * 8;
  double acc[8] = {0,0,0,0,0,0,0,0};
  for (int j = 0; j < 256; ++j){
    double b = B[(size_t)j*256 + c];
    #pragma unroll
    for (int q = 0; q < 8; ++q) acc[q] += A[(size_t)(r0+q)*256 + j] * b;
  }
  #pragma unroll
  for (int q = 0; q < 8; ++q)
    Yn[(size_t)s*65536 + (size_t)(r0+q)*256 + c] =
      2.0 * A[(size_t)(r0+q)*256 + c] - acc[q];
}

// Ad = 2*Minv - I (f32, into AP0); Bd = Minv @ (dt*B); V row0 = Bd
__global__ void k_final(const double* __restrict__ Y, float* __restrict__ Ad,
                        float* __restrict__ Bd, float* __restrict__ V){
  int s = blockIdx.y;
  const double* Ys = Y + (size_t)s*65536;
  if (blockIdx.x < 64){
    int c = threadIdx.x, r0 = blockIdx.x * 4;
    #pragma unroll
    for (int q = 0; q < 4; ++q){
      double v = 2.0 * Ys[(size_t)(r0+q)*256 + c] - ((r0+q) == c ? 1.0 : 0.0);
      Ad[(size_t)s*65536 + (size_t)(r0+q)*256 + c] = (float)v;
    }
  } else {
    int i = threadIdx.x;
    double dt = (1.0 / 192.0) / (double)(1 << s);
    double acc = 0.0;
    for (int j = 0; j < 256; ++j){
      double bj = dt * ((j & 1) ? -1.0 : 1.0) * (double)(2*j + 1);
      acc += Ys[(size_t)i*256 + j] * bj;
    }
    float b = (float)acc;
    Bd[s*256 + i] = b;
    V[((size_t)s*768 + 0)*256 + i] = b;
  }
}

// one doubling level: Pout = Pin@Pin (bx<64, skipped if noSquare);
// V[L..min(2L,768)) = Pin @ V[0..L) (bx>=64)
__global__ void k_level(const float* __restrict__ Pin, float* __restrict__ Pout,
                        float* __restrict__ V, int L, int noSquare){
  int s = blockIdx.y;
  const float* A = Pin + (size_t)s*65536;
  int bx = blockIdx.x;
  if (bx < 64){
    if (noSquare) return;
    int c = threadIdx.x, r0 = bx * 4;
    float acc[4] = {0,0,0,0};
    for (int k = 0; k < 256; ++k){
      float b = A[(size_t)k*256 + c];
      #pragma unroll
      for (int q = 0; q < 4; ++q) acc[q] += A[(size_t)(r0+q)*256 + k] * b;
    }
    #pragma unroll
    for (int q = 0; q < 4; ++q) Pout[(size_t)s*65536 + (size_t)(r0+q)*256 + c] = acc[q];
  } else {
    int j = threadIdx.x;
    if (j >= L || L + j >= 768) return;
    int r0 = (bx - 64) * 4;
    float* Vs = V + (size_t)s*768*256;
    float acc[4] = {0,0,0,0};
    for (int k = 0; k < 256; ++k){
      float v = Vs[(size_t)j*256 + k];
      #pragma unroll
      for (int q = 0; q < 4; ++q) acc[q] += A[(size_t)(r0+q)*256 + k] * v;
    }
    #pragma unroll
    for (int q = 0; q < 4; ++q) Vs[(size_t)(L+j)*256 + r0 + q] = acc[q];
  }
}

// Wt4[s][i][col], col = (kl*2+ri)*256 + o, kl = 0..31 (all modes in one pass)
__global__ void k_wt(const float* __restrict__ wr, const float* __restrict__ wi,
                     float* __restrict__ Wt4){
  int s = blockIdx.x, i = blockIdx.y, tid = threadIdx.x;
  size_t srcbase = ((size_t)s*256 + i)*256;
  float* dst = Wt4 + ((size_t)s*256 + i)*16384;
  for (int ph = 0; ph < 64; ++ph){
    int col = ph*256 + tid;
    int kl = col >> 9, ri = (col >> 8) & 1, o = col & 255;
    const float* src = ri ? wi : wr;
    dst[col] = src[(srcbase + o)*32 + kl];
  }
}

__device__ __forceinline__ void splitf16(float x, unsigned short &h, unsigned short &l){
  _Float16 hf = (_Float16)x;
  _Float16 lf = (_Float16)(x - (float)hf);
  h = __builtin_bit_cast(unsigned short, hf);
  l = __builtin_bit_cast(unsigned short, lf);
}
__device__ __forceinline__ unsigned int pk(unsigned short a, unsigned short b){
  return (unsigned int)a | ((unsigned int)b << 16);
}

// U4 = V @ Wt4 via fp16 split MFMA.  M in {192,384,768}, N=16384, K=256.
__global__ __launch_bounds__(256) void k_ugemm(const float* __restrict__ V,
                                               const float* __restrict__ Wt4,
                                               float* __restrict__ U){
  int s = blockIdx.z;
  int Ts = 192 << s;
  int mt = blockIdx.y;
  if (mt*64 >= Ts) return;
  int nb = blockIdx.x * 64;
  const float* Vs = V + (size_t)s*768*256;
  const float* Bm = Wt4 + (size_t)s*256*16384;
  __shared__ unsigned int Ah[4*65*4], Al[4*65*4];
  __shared__ unsigned int Bh[4*65*4], Bl[4*65*4];
  int tid = threadIdx.x;
  int lane = tid & 63;
  int w = tid >> 6;
  int m0 = (w >> 1) * 32, n0 = (w & 1) * 32;
  int ml = lane & 15, quad = lane >> 4;
  f32x4 acc[2][2];
  #pragma unroll
  for (int t = 0; t < 2; ++t)
    #pragma unroll
    for (int u = 0; u < 2; ++u) acc[t][u] = (f32x4){0.f,0.f,0.f,0.f};

  int am = tid >> 2, akf = tid & 3;
  int bn = tid & 63, bq = tid >> 6;

  for (int kk = 0; kk < 8; ++kk){
    if (kk) __syncthreads();
    {
      const float* ap = &Vs[(size_t)(mt*64 + am)*256 + kk*32 + akf*8];
      float4 a0 = *(const float4*)ap;
      float4 a1 = *(const float4*)(ap + 4);
      unsigned short h[8], l[8];
      splitf16(a0.x*16.f, h[0], l[0]); splitf16(a0.y*16.f, h[1], l[1]);
      splitf16(a0.z*16.f, h[2], l[2]); splitf16(a0.w*16.f, h[3], l[3]);
      splitf16(a1.x*16.f, h[4], l[4]); splitf16(a1.y*16.f, h[5], l[5]);
      splitf16(a1.z*16.f, h[6], l[6]); splitf16(a1.w*16.f, h[7], l[7]);
      int base = (akf*65 + am)*4;
      *(uint4*)&Ah[base] = make_uint4(pk(h[0],h[1]), pk(h[2],h[3]), pk(h[4],h[5]), pk(h[6],h[7]));
      *(uint4*)&Al[base] = make_uint4(pk(l[0],l[1]), pk(l[2],l[3]), pk(l[4],l[5]), pk(l[6],l[7]));
    }
    {
      unsigned short h[8], l[8];
      #pragma unroll
      for (int j = 0; j < 8; ++j){
        float b = Bm[(size_t)(kk*32 + bq*8 + j)*16384 + nb + bn];
        splitf16(b*65536.f, h[j], l[j]);
      }
      int base = (bq*65 + bn)*4;
      *(uint4*)&Bh[base] = make_uint4(pk(h[0],h[1]), pk(h[2],h[3]), pk(h[4],h[5]), pk(h[6],h[7]));
      *(uint4*)&Bl[base] = make_uint4(pk(l[0],l[1]), pk(l[2],l[3]), pk(l[4],l[5]), pk(l[6],l[7]));
    }
    __syncthreads();
    half8 ah[2], al[2], bh[2], bl[2];
    #pragma unroll
    for (int t = 0; t < 2; ++t){
      int idx = (quad*65 + m0 + 16*t + ml)*4;
      ah[t] = *(const half8*)&Ah[idx];
      al[t] = *(const half8*)&Al[idx];
    }
    #pragma unroll
    for (int u = 0; u < 2; ++u){
      int idx = (quad*65 + n0 + 16*u + ml)*4;
      bh[u] = *(const half8*)&Bh[idx];
      bl[u] = *(const half8*)&Bl[idx];
    }
    #pragma unroll
    for (int t = 0; t < 2; ++t)
      #pragma unroll
      for (int u = 0; u < 2; ++u){
        acc[t][u] = __builtin_amdgcn_mfma_f32_16x16x32_f16(ah[t], bh[u], acc[t][u], 0, 0, 0);
        acc[t][u] = __builtin_amdgcn_mfma_f32_16x16x32_f16(ah[t], bl[u], acc[t][u], 0, 0, 0);
        acc[t][u] = __builtin_amdgcn_mfma_f32_16x16x32_f16(al[t], bh[u], acc[t][u], 0, 0, 0);
      }
  }
  int ub = (s == 0) ? 0 : (s == 1 ? 192 : 576);
  const float unscale = 1.0f / 1048576.0f;   // 2^-20
  #pragma unroll
  for (int t = 0; t < 2; ++t)
    #pragma unroll
    for (int u = 0; u < 2; ++u){
      int row = ub + mt*64 + m0 + 16*t + quad*4;
      int col = nb + n0 + 16*u + ml;
      #pragma unroll
      for (int r = 0; r < 4; ++r)
        U[(size_t)(row + r)*16384 + col] = acc[t][u][r] * unscale;
    }
}

// ---- two-phase parallel scan, all 32 modes ----
__global__ void k_scanA(float* __restrict__ U, float* __restrict__ Seg){
  int seg = blockIdx.x;      // 0..7
  int kl  = blockIdx.y;      // 0..31
  int s   = blockIdx.z;      // 0..2
  int k = kl;
  int T = 192 << s;
  int Ls = T >> 3;
  int m0 = seg * Ls;
  int ub = (s == 0) ? 0 : (s == 1 ? 192 : 576);
  int o = threadIdx.x;
  float* Ur = U + ((size_t)(ub + m0))*16384 + kl*512 + o;
  float th = 6.283185307179586f / (float)T;
  int im = (k * m0) % T;
  float Zr = 0.f, Zi = 0.f;
  #pragma unroll 4
  for (int i = 0; i < Ls; ++i){
    float ur = Ur[0];
    float ui = Ur[256];
    float sa, ca; __sincosf(th * (float)im, &sa, &ca);
    Zr += ca*ur + sa*ui;
    Zi += ca*ui - sa*ur;
    Ur[0] = Zr; Ur[256] = Zi;
    im += k; if (im >= T) im -= T;
    Ur += 16384;
  }
  float* Sg = Seg + (((size_t)(s*32 + kl)*8 + seg)*2)*256 + o;
  Sg[0] = Zr; Sg[256] = Zi;
}

__global__ void k_scanC(const float* __restrict__ U, const float* __restrict__ Seg,
                        float* __restrict__ C32){
  int seg = blockIdx.x, kl = blockIdx.y, s = blockIdx.z;
  int k = kl;
  int T = 192 << s;
  int Ls = T >> 3;
  int m0 = seg * Ls;
  int ub = (s == 0) ? 0 : (s == 1 ? 192 : 576);
  int o = threadIdx.x;
  float offr = 0.f, offi = 0.f;
  const float* Sg = Seg + ((size_t)(s*32 + kl)*8)*512 + o;
  for (int j = 0; j < seg; ++j){ offr += Sg[(size_t)j*512]; offi += Sg[(size_t)j*512 + 256]; }
  const float* Ur = U + ((size_t)(ub + m0))*16384 + kl*512 + o;
  float* Cb = C32 + ((size_t)kl*1344 + ub)*256 + o;
  float ckT = ((k == 0) ? 1.0f : 2.0f) / (float)T;
  float th = 6.283185307179586f / (float)T;
  int ib = (k * (192 + m0)) % T;
  #pragma unroll 4
  for (int i = 0; i < Ls; ++i){
    int m = m0 + i;
    float zr = offr + Ur[0];
    float zi = offi + Ur[256];
    float sb, cb; __sincosf(th * (float)ib, &sb, &cb);
    Cb[(size_t)(T-1-m)*256] = ckT * (zr*cb - zi*sb);
    ib += k; if (ib >= T) ib -= T;
    Ur += 16384;
  }
}

// P[row][o] = sum_kl C32[kl][row][o]
__global__ void k_reduce(const float* __restrict__ C32, float* __restrict__ P){
  int row = blockIdx.x;    // 0..1343
  int o = threadIdx.x;
  float a = 0.f;
  #pragma unroll
  for (int kl = 0; kl < 32; ++kl) a += C32[((size_t)kl*1344 + row)*256 + o];
  P[(size_t)row*256 + o] = a;
}

// K[to][tg] = sum_s mlpw[s] * sum_o em[s][to][o] * P[s][tg-off][o]
// 64x64-tile LDS GEMM; grid (12, 3): y = 64-row to-tile.
__global__ __launch_bounds__(256) void k_K(const float* __restrict__ em,
                                           const float* __restrict__ P,
                                           const float* __restrict__ mlpw,
                                           float* __restrict__ K){
  int tn = blockIdx.x;
  int tmb = blockIdx.y;
  __shared__ float Es[16][68];
  __shared__ float Ps[16][68];
  int tid = threadIdx.x;
  int tm = tid >> 4, tnn = tid & 15;
  int srow = tid >> 2;
  int acol4 = (tid & 3) * 4;
  float acc[4][4];
  #pragma unroll
  for (int a = 0; a < 4; ++a)
    #pragma unroll
    for (int b = 0; b < 4; ++b) acc[a][b] = 0.f;
  for (int s = 0; s < 3; ++s){
    int T = 192 << s;
    int off = 768 - T;
    if (tn*64 < off) continue;
    int ub = (s == 0) ? 0 : (s == 1 ? 192 : 576);
    float mw = mlpw[s];
    const float* ems = em + ((size_t)s*192 + tmb*64)*256;
    const float* Pb = P + ((size_t)ub + (tn*64 - off))*256;
    float sacc[4][4];
    #pragma unroll
    for (int a = 0; a < 4; ++a)
      #pragma unroll
      for (int b = 0; b < 4; ++b) sacc[a][b] = 0.f;
    for (int k0 = 0; k0 < 256; k0 += 16){
      float4 e4 = *(const float4*)&ems[(size_t)srow*256 + k0 + acol4];
      Es[acol4+0][srow] = e4.x; Es[acol4+1][srow] = e4.y;
      Es[acol4+2][srow] = e4.z; Es[acol4+3][srow] = e4.w;
      float4 p4 = *(const float4*)&Pb[(size_t)srow*256 + k0 + acol4];
      Ps[acol4+0][srow] = p4.x; Ps[acol4+1][srow] = p4.y;
      Ps[acol4+2][srow] = p4.z; Ps[acol4+3][srow] = p4.w;
      __syncthreads();
      #pragma unroll
      for (int k = 0; k < 16; ++k){
        float av[4], bv[4];
        *(float4*)av = *(const float4*)&Es[k][tm*4];
        *(float4*)bv = *(const float4*)&Ps[k][tnn*4];
        #pragma unroll
        for (int a = 0; a < 4; ++a)
          #pragma unroll
          for (int b = 0; b < 4; ++b) sacc[a][b] += av[a]*bv[b];
      }
      __syncthreads();
    }
    #pragma unroll
    for (int a = 0; a < 4; ++a)
      #pragma unroll
      for (int b = 0; b < 4; ++b) acc[a][b] += mw * sacc[a][b];
  }
  int to0 = tmb*64 + tm*4;
  int tg0 = tn*64 + tnn*4;
  #pragma unroll
  for (int a = 0; a < 4; ++a){
    float4 o4 = make_float4(acc[a][0], acc[a][1], acc[a][2], acc[a][3]);
    *(float4*)&K[(size_t)(to0+a)*768 + tg0] = o4;
  }
}

// out[b][to][d] = mlp_b + sum_t K[to][t] * inputs[b][t][d]
__global__ __launch_bounds__(256) void k_out(const float* __restrict__ K,
                                             const float* __restrict__ inp,
                                             const float* __restrict__ mlpb,
                                             float* __restrict__ out){
  int to = blockIdx.x, b = blockIdx.y;
  int d = threadIdx.x & 63;
  int w = threadIdx.x >> 6;
  const float* Kr = K + (size_t)to*768 + w*192;
  const float* ip = inp + (size_t)b*768*64 + (size_t)(w*192)*64 + d;
  float acc = 0.f;
  #pragma unroll 4
  for (int i = 0; i < 192; ++i) acc += Kr[i] * ip[(size_t)i*64];
  __shared__ float red[4][64];
  red[w][d] = acc;
  __syncthreads();
  if (w == 0)
    out[((size_t)b*192 + to)*64 + d] =
      red[0][d] + red[1][d] + red[2][d] + red[3][d] + mlpb[0];
}

extern "C" void kernel_launch(void* const* d_in, const int* in_sizes, int n_in,
                              void* d_out, int out_size, void* d_ws, size_t ws_size,
                              hipStream_t stream){
  const float* inputs  = (const float*)d_in[0];
  const float* spec_wr = (const float*)d_in[1];
  const float* spec_wi = (const float*)d_in[2];
  const float* mlp_w   = (const float*)d_in[3];
  const float* mlp_b   = (const float*)d_in[4];
  float* out = (float*)d_out;
  char* ws = (char*)d_ws;

  double* Mf64 = (double*)(ws + OFF_MF64);
  double* Ya   = (double*)(ws + OFF_YA);
  double* Yb   = (double*)(ws + OFF_YB);
  double* Zb   = (double*)(ws + OFF_Z);
  float* W0   = (float*)(ws + OFF_W0);
  float* Fg   = (float*)(ws + OFF_F);
  int*   pivg = (int*)(ws + OFF_PIV);
  int*   flags= (int*)(ws + OFF_FLAG);
  float* AP0  = (float*)(ws + OFF_AP0);
  float* AP1  = (float*)(ws + OFF_AP1);
  float* Bd   = (float*)(ws + OFF_BD);
  float* V    = (float*)(ws + OFF_V);
  float* em   = (float*)(ws + OFF_EM);
  float* P    = (float*)(ws + OFF_P);
  float* Km   = (float*)(ws + OFF_K);
  float* U4   = (float*)(ws + OFF_U4);
  float* Wt4  = (float*)(ws + OFF_WT4);
  float* C32  = (float*)(ws + OFF_C32);
  float* Seg4 = (float*)(ws + OFF_SEG4);

  k_init<<<dim3(257,3), 256, 0, stream>>>(Mf64, em, flags);
  k_gj<<<48, 256, 0, stream>>>(W0, Fg, pivg, flags);
  k_y0<<<dim3(256,3), 256, 0, stream>>>(W0, pivg, Ya);
  for (int it = 0; it < 2; ++it){
    double* yi = (it & 1) ? Yb : Ya;
    double* yo = (it & 1) ? Ya : Yb;
    k_mmZ<<<dim3(32,3), 256, 0, stream>>>(Mf64, yi, Zb);
    k_mmN<<<dim3(32,3), 256, 0, stream>>>(yi, Zb, yo);
  }
  // refined Minv in Ya (2 Newton iters: Ya->Yb->Ya)
  k_final<<<dim3(65,3), 256, 0, stream>>>(Ya, AP0, Bd, V);

  // Krylov: doubling all the way (V[L..2L) = A^L V[0..L)); last level needs no square
  float* pin = AP0; float* pout = AP1;
  for (int L = 1; L <= 512; L <<= 1){
    k_level<<<dim3(128,3), 256, 0, stream>>>(pin, pout, V, L, (L == 512) ? 1 : 0);
    float* t = pin; pin = pout; pout = t;
  }

  k_wt<<<dim3(3,256), 256, 0, stream>>>(spec_wr, spec_wi, Wt4);
  k_ugemm<<<dim3(256,12,3), 256, 0, stream>>>(V, Wt4, U4);
  k_scanA<<<dim3(8,32,3), 256, 0, stream>>>(U4, Seg4);
  k_scanC<<<dim3(8,32,3), 256, 0, stream>>>(U4, Seg4, C32);
  k_reduce<<<1344, 256, 0, stream>>>(C32, P);
  k_K<<<dim3(12,3), 256, 0, stream>>>(em, P, mlp_w, Km);
  k_out<<<dim3(192,8), 256, 0, stream>>>(Km, inputs, mlp_b, out);
}